// Round 14
// baseline (176.116 us; speedup 1.0000x reference)
//
#include <hip/hip_runtime.h>
#include <math.h>

#define LSEQ 4096
#define D_IN 8
#define D_MODEL 256
#define ED 512
#define NSTATE 16
#define KCONV 4
#define DT_RANK 16
#define EPS 1e-5f
#define NCHUNK 256
#define CHUNK 16   /* LSEQ / NCHUNK */

typedef short short8 __attribute__((ext_vector_type(8)));
typedef unsigned short ushort8 __attribute__((ext_vector_type(8)));
typedef unsigned short ushort4v __attribute__((ext_vector_type(4)));
typedef float f32x4 __attribute__((ext_vector_type(4)));

__device__ __forceinline__ float sigmoidf_(float x){ return 1.f/(1.f+__expf(-x)); }
__device__ __forceinline__ float siluf_(float x){ return x*sigmoidf_(x); }
__device__ __forceinline__ float softplusf_(float x){
  return (x > 20.f) ? x : log1pf(__expf(x));
}
__device__ __forceinline__ unsigned short f2bf(float f){
  unsigned int u = __float_as_uint(f);
  return (unsigned short)((u + 0x7fffu + ((u>>16)&1u)) >> 16);
}
__device__ __forceinline__ float bf2f(unsigned short u){
  return __uint_as_float(((unsigned int)u) << 16);
}

// ---- prep: vectorized weight bf16 conversion (blocks 0..815) + fc_in (816..4911) ----
__global__ void k_prep(const float* __restrict__ x, const float* __restrict__ fiw,
                       const float* __restrict__ fib, const float* __restrict__ ipw,
                       const float* __restrict__ xpw, const float* __restrict__ opw,
                       float* __restrict__ h, unsigned short* __restrict__ wip,
                       unsigned short* __restrict__ wxp, unsigned short* __restrict__ wop){
  int b = blockIdx.x, tid = threadIdx.x;
  if (b < 816) {
    int i4 = b*256 + tid;
    const float* src; unsigned short* dst;
    if (i4 < 131072)      { src = ipw; dst = wip; }
    else if (i4 < 143360) { i4 -= 131072; src = xpw; dst = wxp; }
    else                  { i4 -= 143360; src = opw; dst = wop; }
    float4 v = ((const float4*)src)[i4];
    ushort4v o;
    o.x = f2bf(v.x); o.y = f2bf(v.y); o.z = f2bf(v.z); o.w = f2bf(v.w);
    ((ushort4v*)dst)[i4] = o;
  } else {
    int idx = (b-816)*256 + tid;               // t*256 + d
    int t = idx >> 8, d = idx & 255;
    float acc = fib[d];
#pragma unroll
    for (int i = 0; i < D_IN; ++i) acc += x[t*D_IN+i]*fiw[d*D_IN+i];
    h[idx] = acc;
  }
}

// ---- bf16 MFMA GEMM, BK=64: C[MxN] (+)= A[MxK] @ B[NxK]^T ----
template<int WM, int WN, bool RMS, bool ACC, bool ABF16, bool CBF16>
__global__ __launch_bounds__(256) void k_gemm_mfma(
    const void* __restrict__ Ap, const unsigned short* __restrict__ B,
    void* __restrict__ Cp, int M, int N, int K, const float* __restrict__ nwp)
{
  constexpr int BM = 32*WM, BN = 32*WN, LDT = 72;   // 64 + 8 pad (16B-aligned rows)
  const float* A = (const float*)Ap;
  const unsigned short* Ab = (const unsigned short*)Ap;
  float* Cf = (float*)Cp;
  unsigned short* Cb = (unsigned short*)Cp;
  __shared__ unsigned short As[BM*LDT];
  __shared__ unsigned short Bs[BN*LDT];
  __shared__ float rms_lds[BM];
  __shared__ float nws[D_MODEL];
  const int tid = threadIdx.x;
  const int bm = blockIdx.x*BM, bn = blockIdx.y*BN;
  const int w = tid >> 6, lane = tid & 63;
  const int mb = (w>>1)*WM*16, nb = (w&1)*WN*16;
  const int lr = lane & 15, lk = (lane>>4)*8;
  if (RMS) {
    nws[tid] = nwp[tid];                       // 256 threads == D_MODEL
    constexpr int TPR = 256/BM;                // threads per row
    constexpr int SEG = D_MODEL/TPR;           // cols per thread
    int row = tid / TPR, part = tid % TPR;
    const float* ap = A + (size_t)(bm+row)*K + part*SEG;
    float s = 0.f;
#pragma unroll
    for (int i = 0; i < SEG; i += 4) {
      float4 v = *(const float4*)&ap[i];
      s += v.x*v.x + v.y*v.y + v.z*v.z + v.w*v.w;
    }
#pragma unroll
    for (int m = TPR>>1; m; m >>= 1) s += __shfl_xor(s, m);
    if (part == 0) rms_lds[row] = rsqrtf(s*(1.f/D_MODEL) + EPS);
    __syncthreads();
  }
  f32x4 acc[WM][WN] = {};
  for (int k0 = 0; k0 < K; k0 += 64) {
#pragma unroll 2
    for (int s = tid; s < BM*8; s += 256) {
      int row = s>>3, kg = (s&7)*8;
      if (ABF16) {
        *(ushort8*)&As[row*LDT+kg] = *(const ushort8*)&Ab[(size_t)(bm+row)*K + k0 + kg];
      } else {
        const float* ap = &A[(size_t)(bm+row)*K + k0 + kg];
        float4 a0 = *(const float4*)ap, a1 = *(const float4*)(ap+4);
        if (RMS) {
          float rs = rms_lds[row];
          a0.x *= rs*nws[k0+kg+0]; a0.y *= rs*nws[k0+kg+1];
          a0.z *= rs*nws[k0+kg+2]; a0.w *= rs*nws[k0+kg+3];
          a1.x *= rs*nws[k0+kg+4]; a1.y *= rs*nws[k0+kg+5];
          a1.z *= rs*nws[k0+kg+6]; a1.w *= rs*nws[k0+kg+7];
        }
        ushort8 o;
        o[0]=f2bf(a0.x); o[1]=f2bf(a0.y); o[2]=f2bf(a0.z); o[3]=f2bf(a0.w);
        o[4]=f2bf(a1.x); o[5]=f2bf(a1.y); o[6]=f2bf(a1.z); o[7]=f2bf(a1.w);
        *(ushort8*)&As[row*LDT+kg] = o;
      }
    }
#pragma unroll 2
    for (int s = tid; s < BN*8; s += 256) {
      int row = s>>3, kg = (s&7)*8;
      *(ushort8*)&Bs[row*LDT+kg] = *(const ushort8*)&B[(size_t)(bn+row)*K + k0 + kg];
    }
    __syncthreads();
#pragma unroll
    for (int kk = 0; kk < 2; ++kk) {
      short8 af[WM], bfr[WN];
#pragma unroll
      for (int i = 0; i < WM; ++i) af[i]  = *(const short8*)&As[(mb+i*16+lr)*LDT + kk*32 + lk];
#pragma unroll
      for (int j = 0; j < WN; ++j) bfr[j] = *(const short8*)&Bs[(nb+j*16+lr)*LDT + kk*32 + lk];
#pragma unroll
      for (int i = 0; i < WM; ++i)
#pragma unroll
        for (int j = 0; j < WN; ++j)
          acc[i][j] = __builtin_amdgcn_mfma_f32_16x16x32_bf16(af[i], bfr[j], acc[i][j], 0, 0, 0);
    }
    __syncthreads();
  }
  // D layout: col = lane&15, row = (lane>>4)*4 + r
#pragma unroll
  for (int i = 0; i < WM; ++i)
#pragma unroll
    for (int j = 0; j < WN; ++j) {
      int col = bn + nb + j*16 + lr;
#pragma unroll
      for (int r = 0; r < 4; ++r) {
        int row = bm + mb + i*16 + (lane>>4)*4 + r;
        size_t o = (size_t)row*N + col;
        if (CBF16)      Cb[o] = f2bf(acc[i][j][r]);
        else if (ACC)   Cf[o] = Cf[o] + acc[i][j][r];
        else            Cf[o] = acc[i][j][r];
      }
    }
}

// ---- conv + silu + x_proj + dt_proj + scan phase 1, one block per 16-row chunk ----
// xi rows (t0-3..t0+15) staged to LDS with ushort8 coalesced loads (G13); conv reads LDS.
__global__ __launch_bounds__(512) void k_cxps1(
    const unsigned short* __restrict__ xzb, const float* __restrict__ cw,
    const float* __restrict__ cb, const unsigned short* __restrict__ wxp,
    const float* __restrict__ dtw, const float* __restrict__ dtb,
    const float* __restrict__ alog, float* __restrict__ dbc,
    float* __restrict__ S, unsigned short* __restrict__ Q)
{
  constexpr int LDA = ED + 8;   // 520 ushorts per row
  __shared__ unsigned short As[CHUNK*LDA];
  __shared__ unsigned short Xi[(CHUNK+3)*ED];   // 19 rows of xi half
  __shared__ float Ds[CHUNK][DT_RANK];
  __shared__ float Bsh[CHUNK][NSTATE];
  const int tid = threadIdx.x;
  const int e = tid;
  const int c = blockIdx.x;
  const int t0 = c*CHUNK;
  // stage xi rows t0-3 .. t0+15 (zero-fill t<0) with 16B coalesced loads
  for (int i = tid; i < (CHUNK+3)*(ED/8); i += 512) {
    int row = i >> 6, col8 = (i & 63)*8;       // ED/8 == 64
    int t = t0 - 3 + row;
    ushort8 v = {0,0,0,0,0,0,0,0};
    if (t >= 0) v = *(const ushort8*)&xzb[(size_t)t*(2*ED) + col8];
    *(ushort8*)&Xi[row*ED + col8] = v;
  }
  float cwv[KCONV];
#pragma unroll
  for (int k = 0; k < KCONV; ++k) cwv[k] = cw[e*KCONV+k];
  float cbv = cb[e];
  __syncthreads();
  float w0 = bf2f(Xi[0*ED + e]), w1 = bf2f(Xi[1*ED + e]), w2 = bf2f(Xi[2*ED + e]);
  float xv[CHUNK];
#pragma unroll
  for (int t = 0; t < CHUNK; ++t) {
    float cur = bf2f(Xi[(3+t)*ED + e]);
    float v = siluf_(cbv + w0*cwv[0] + w1*cwv[1] + w2*cwv[2] + cur*cwv[3]);
    xv[t] = v;
    w0=w1; w1=w2; w2=cur;
  }
#pragma unroll
  for (int t = 0; t < CHUNK; ++t) {
    unsigned int us = f2bf(xv[t]);
    unsigned int other = (unsigned int)__shfl_down((int)us, 1);
    if ((tid & 1) == 0) *(unsigned int*)&As[t*LDA + e] = us | (other << 16);
  }
  __syncthreads();
  const int w = tid >> 6, lane = tid & 63;
  const int lr = lane & 15, lk = (lane>>4)*8;
  if (w < 3) {
    f32x4 acc = {};
#pragma unroll
    for (int ks = 0; ks < ED/32; ++ks) {
      short8 af = *(const short8*)&As[lr*LDA + ks*32 + lk];
      short8 bf = *(const short8*)&wxp[(size_t)(w*16+lr)*ED + ks*32 + lk];
      acc = __builtin_amdgcn_mfma_f32_16x16x32_bf16(af, bf, acc, 0, 0, 0);
    }
#pragma unroll
    for (int r = 0; r < 4; ++r) {
      int row = (lane>>4)*4 + r;
      dbc[(size_t)(t0+row)*48 + w*16 + lr] = acc[r];
      if (w == 0) Ds[row][lr] = acc[r];
      else if (w == 1) Bsh[row][lr] = acc[r];
    }
  }
  __syncthreads();
  float dtwv[DT_RANK];
#pragma unroll
  for (int r = 0; r < DT_RANK; ++r) dtwv[r] = dtw[e*DT_RANK+r];
  float dtbv = dtb[e];
  float A[NSTATE], h[NSTATE];
#pragma unroll
  for (int n = 0; n < NSTATE; ++n) { A[n] = -__expf(alog[e*NSTATE+n]); h[n] = 0.f; }
  float sd = 0.f;
#pragma unroll
  for (int t = 0; t < CHUNK; ++t) {
    float da = dtbv;
#pragma unroll
    for (int r = 0; r < DT_RANK; ++r) da += Ds[t][r]*dtwv[r];
    float d = softplusf_(da);
    sd += d;
    float dx = d*xv[t];
#pragma unroll
    for (int n = 0; n < NSTATE; ++n)
      h[n] = __expf(d*A[n])*h[n] + dx*Bsh[t][n];
  }
  S[(size_t)c*ED + e] = sd;
#pragma unroll
  for (int n = 0; n < NSTATE; ++n) Q[(size_t)(c*NSTATE+n)*ED + e] = f2bf(h[n]);
}

// Phase 2: segmented affine scan. 256 blocks x 512 thr; block = 32 channels x 16 segs.
__global__ __launch_bounds__(512) void k_scan2(
    const float* __restrict__ alog, const float* __restrict__ S,
    unsigned short* __restrict__ Q)
{
  constexpr int NSEG = 16, STEPS = NCHUNK/NSEG;   // 16 x 16
  __shared__ float Pl[NSEG][32], Rl[NSEG][32], Hs[NSEG][32];
  const int tid = threadIdx.x;
  const int seg = tid >> 5, chl = tid & 31;
  const int ch = blockIdx.x*32 + chl;
  const int n = ch >> 9, e = ch & 511;
  const float a = -__expf(alog[e*NSTATE+n]);
  const int c0 = seg*STEPS;
  float ev[STEPS], qv[STEPS];
#pragma unroll
  for (int k = 0; k < STEPS; ++k) ev[k] = S[(size_t)(c0+k)*ED + e];
#pragma unroll
  for (int k = 0; k < STEPS; ++k) qv[k] = bf2f(Q[(size_t)((c0+k)*NSTATE+n)*ED + e]);
#pragma unroll
  for (int k = 0; k < STEPS; ++k) ev[k] = __expf(a*ev[k]);
  float P = 1.f, R = 0.f;
#pragma unroll
  for (int k = 0; k < STEPS; ++k) { R = ev[k]*R + qv[k]; P *= ev[k]; }
  Pl[seg][chl] = P; Rl[seg][chl] = R;
  __syncthreads();
  if (tid < 32) {
    float hcur = 0.f;
#pragma unroll
    for (int s = 0; s < NSEG; ++s) { Hs[s][tid] = hcur; hcur = Pl[s][tid]*hcur + Rl[s][tid]; }
  }
  __syncthreads();
  float h = Hs[seg][chl];
#pragma unroll
  for (int k = 0; k < STEPS; ++k) {
    float hl = qv[k];
    Q[(size_t)((c0+k)*NSTATE+n)*ED + e] = f2bf(h);
    h = ev[k]*h + hl;
  }
}

// Phase 3: xi/z staged to LDS (ushort8 coalesced); conv recompute (bit-identical);
// replay with true Hin (bf16); fuse dt_proj, C-dot, D-skip, silu(z); packed y stores.
__global__ __launch_bounds__(512) void k_scan3(
    const unsigned short* __restrict__ xzb, const float* __restrict__ dbc,
    const float* __restrict__ cw, const float* __restrict__ cb,
    const float* __restrict__ dtw, const float* __restrict__ dtb,
    const float* __restrict__ alog, const unsigned short* __restrict__ Hin,
    const float* __restrict__ Dv, unsigned short* __restrict__ y)
{
  __shared__ float Ds[CHUNK][DT_RANK];
  __shared__ float Bsh[CHUNK][NSTATE];
  __shared__ float Cs[CHUNK][NSTATE];
  __shared__ unsigned short Xi[(CHUNK+3)*ED];   // 19 rows of xi half
  __shared__ unsigned short Zs[CHUNK*ED];       // 16 rows of z half
  const int tid = threadIdx.x;
  const int e = tid;
  const int c = blockIdx.x;
  const int t0 = c*CHUNK;
  // hoisted independent loads
  float A[NSTATE], h[NSTATE];
#pragma unroll
  for (int n = 0; n < NSTATE; ++n) {
    A[n] = -__expf(alog[e*NSTATE+n]);
    h[n] = bf2f(Hin[(size_t)(c*NSTATE+n)*ED + e]);
  }
  float dtwv[DT_RANK];
#pragma unroll
  for (int r = 0; r < DT_RANK; ++r) dtwv[r] = dtw[e*DT_RANK+r];
  float dtbv = dtb[e];
  float dv = Dv[e];
  float cwv[KCONV];
#pragma unroll
  for (int k = 0; k < KCONV; ++k) cwv[k] = cw[e*KCONV+k];
  float cbv = cb[e];
  // stage dbc
  for (int i = tid; i < CHUNK*48; i += 512) {
    int t = i/48, col = i - t*48;
    float v = dbc[(size_t)(t0+t)*48 + col];
    if (col < DT_RANK) Ds[t][col] = v;
    else if (col < DT_RANK+NSTATE) Bsh[t][col-DT_RANK] = v;
    else Cs[t][col-DT_RANK-NSTATE] = v;
  }
  // stage xi rows t0-3 .. t0+15 (zero-fill t<0)
  for (int i = tid; i < (CHUNK+3)*(ED/8); i += 512) {
    int row = i >> 6, col8 = (i & 63)*8;
    int t = t0 - 3 + row;
    ushort8 v = {0,0,0,0,0,0,0,0};
    if (t >= 0) v = *(const ushort8*)&xzb[(size_t)t*(2*ED) + col8];
    *(ushort8*)&Xi[row*ED + col8] = v;
  }
  // stage z rows t0 .. t0+15
  for (int i = tid; i < CHUNK*(ED/8); i += 512) {
    int row = i >> 6, col8 = (i & 63)*8;
    *(ushort8*)&Zs[row*ED + col8] =
      *(const ushort8*)&xzb[(size_t)(t0+row)*(2*ED) + ED + col8];
  }
  __syncthreads();
  // conv recompute from LDS (same bf16 bits as k_cxps1 -> identical fp32 values)
  float w0 = bf2f(Xi[0*ED + e]), w1 = bf2f(Xi[1*ED + e]), w2 = bf2f(Xi[2*ED + e]);
  float x[CHUNK], z[CHUNK];
#pragma unroll
  for (int t = 0; t < CHUNK; ++t) {
    float cur = bf2f(Xi[(3+t)*ED + e]);
    x[t] = siluf_(cbv + w0*cwv[0] + w1*cwv[1] + w2*cwv[2] + cur*cwv[3]);
    w0=w1; w1=w2; w2=cur;
  }
#pragma unroll
  for (int t = 0; t < CHUNK; ++t) z[t] = bf2f(Zs[t*ED + e]);
#pragma unroll
  for (int t = 0; t < CHUNK; ++t) {
    float da = dtbv;
#pragma unroll
    for (int r = 0; r < DT_RANK; ++r) da += Ds[t][r]*dtwv[r];
    float d = softplusf_(da);
    float dx = d*x[t];
    float ysum = 0.f;
#pragma unroll
    for (int n = 0; n < NSTATE; ++n) {
      h[n] = __expf(d*A[n])*h[n] + dx*Bsh[t][n];
      ysum += h[n]*Cs[t][n];
    }
    // pair-packed bf16 store: even lane writes 4B for (e, e+1)
    unsigned int us = f2bf((ysum + dv*x[t]) * siluf_(z[t]));
    unsigned int other = (unsigned int)__shfl_down((int)us, 1);
    if ((tid & 1) == 0)
      *(unsigned int*)&y[(size_t)(t0+t)*ED + e] = us | (other << 16);
  }
}

// out[t] = tanh( h[t][:] . fc_out_w + fc_out_b ) — one wave per row
__global__ void k_fc_out(const float* __restrict__ h, const float* __restrict__ w,
                         const float* __restrict__ b, float* __restrict__ out){
  int wave = threadIdx.x >> 6, lane = threadIdx.x & 63;
  int row = blockIdx.x*4 + wave;
  const float4 hv = *(const float4*)&h[row*D_MODEL + lane*4];
  const float4 wv = *(const float4*)&w[lane*4];
  float s = hv.x*wv.x + hv.y*wv.y + hv.z*wv.z + hv.w*wv.w;
#pragma unroll
  for (int m = 32; m; m >>= 1) s += __shfl_xor(s, m);
  if (lane == 0) out[row] = tanhf(s + b[0]);
}

extern "C" void kernel_launch(void* const* d_in, const int* in_sizes, int n_in,
                              void* d_out, int out_size, void* d_ws, size_t ws_size,
                              hipStream_t stream){
  const float* x    = (const float*)d_in[0];
  const float* fiw  = (const float*)d_in[1];
  const float* fib  = (const float*)d_in[2];
  const float* fow  = (const float*)d_in[3];
  const float* fob  = (const float*)d_in[4];
  const float* nw   = (const float*)d_in[5];
  const float* ipw  = (const float*)d_in[6];
  const float* cw   = (const float*)d_in[7];
  const float* cb   = (const float*)d_in[8];
  const float* xpw  = (const float*)d_in[9];
  const float* dtw  = (const float*)d_in[10];
  const float* dtb  = (const float*)d_in[11];
  const float* alog = (const float*)d_in[12];
  const float* Dv   = (const float*)d_in[13];
  const float* opw  = (const float*)d_in[14];

  float* W = (float*)d_ws;
  float* h   = W;                                   // L*256 fp32
  float* dbc = h   + (size_t)LSEQ*D_MODEL;          // L*48 fp32
  float* S   = dbc + (size_t)LSEQ*48;               // 256*512 fp32
  unsigned short* xzb = (unsigned short*)(S + (size_t)NCHUNK*ED); // L*1024 bf16
  unsigned short* Q   = xzb + (size_t)LSEQ*2*ED;    // 256*16*512 bf16 (Hin in-place)
  unsigned short* yb  = Q   + (size_t)NCHUNK*NSTATE*ED; // L*512 bf16
  unsigned short* wip = yb  + (size_t)LSEQ*ED;      // 2*1024*256
  unsigned short* wxp = wip + (size_t)2*2*ED*D_MODEL; // 2*48*512
  unsigned short* wop = wxp + (size_t)2*48*ED;      // 2*256*512

  k_prep<<<816 + LSEQ, 256, 0, stream>>>(x, fiw, fib, ipw, xpw, opw, h, wip, wxp, wop);

  for (int l = 0; l < 2; ++l) {
    const unsigned short* wip_l = wip + (size_t)l*2*ED*D_MODEL;
    const unsigned short* wxp_l = wxp + (size_t)l*48*ED;
    const unsigned short* wop_l = wop + (size_t)l*D_MODEL*ED;
    const float* nw_l   = nw   + l*D_MODEL;
    const float* cw_l   = cw   + l*ED*KCONV;
    const float* cb_l   = cb   + l*ED;
    const float* dtw_l  = dtw  + l*ED*DT_RANK;
    const float* dtb_l  = dtb  + l*ED;
    const float* alog_l = alog + l*ED*NSTATE;
    const float* D_l    = Dv   + l*ED;

    // in_proj: BM=BN=64 -> 64x16 = 1024 blocks (4 blocks/CU, latency-hiding)
    k_gemm_mfma<2,2,true,false,false,true><<<dim3(LSEQ/64, (2*ED)/64), 256, 0, stream>>>(
        h, wip_l, xzb, LSEQ, 2*ED, D_MODEL, nw_l);
    k_cxps1<<<NCHUNK, 512, 0, stream>>>(xzb, cw_l, cb_l, wxp_l, dtw_l, dtb_l, alog_l,
                                        dbc, S, Q);
    k_scan2<<<ED*NSTATE/32, 512, 0, stream>>>(alog_l, S, Q);
    k_scan3<<<NCHUNK, 512, 0, stream>>>(xzb, dbc, cw_l, cb_l, dtw_l, dtb_l, alog_l,
                                        Q, D_l, yb);
    // out_proj: BM=BN=32 -> 128x8 = 1024 blocks (4 blocks/CU)
    k_gemm_mfma<1,1,false,true,true,false><<<dim3(LSEQ/32, D_MODEL/32), 256, 0, stream>>>(
        yb, wop_l, h, LSEQ, D_MODEL, ED, nullptr);
  }

  k_fc_out<<<LSEQ/4, 256, 0, stream>>>(h, fow, fob, (float*)d_out);
}

// Round 15
// 169.765 us; speedup vs baseline: 1.0374x; 1.0374x over previous
//
#include <hip/hip_runtime.h>
#include <math.h>

#define LSEQ 4096
#define D_IN 8
#define D_MODEL 256
#define ED 512
#define NSTATE 16
#define KCONV 4
#define DT_RANK 16
#define EPS 1e-5f
#define NCHUNK 256
#define CHUNK 16   /* LSEQ / NCHUNK */

typedef short short8 __attribute__((ext_vector_type(8)));
typedef unsigned short ushort8 __attribute__((ext_vector_type(8)));
typedef unsigned short ushort4v __attribute__((ext_vector_type(4)));
typedef float f32x4 __attribute__((ext_vector_type(4)));

__device__ __forceinline__ float sigmoidf_(float x){ return 1.f/(1.f+__expf(-x)); }
__device__ __forceinline__ float siluf_(float x){ return x*sigmoidf_(x); }
__device__ __forceinline__ float softplusf_(float x){
  return (x > 20.f) ? x : log1pf(__expf(x));
}
__device__ __forceinline__ unsigned short f2bf(float f){
  unsigned int u = __float_as_uint(f);
  return (unsigned short)((u + 0x7fffu + ((u>>16)&1u)) >> 16);
}
__device__ __forceinline__ float bf2f(unsigned short u){
  return __uint_as_float(((unsigned int)u) << 16);
}

// ---- prep: vectorized weight bf16 conversion (blocks 0..815) + fc_in (816..4911) ----
__global__ void k_prep(const float* __restrict__ x, const float* __restrict__ fiw,
                       const float* __restrict__ fib, const float* __restrict__ ipw,
                       const float* __restrict__ xpw, const float* __restrict__ opw,
                       float* __restrict__ h, unsigned short* __restrict__ wip,
                       unsigned short* __restrict__ wxp, unsigned short* __restrict__ wop){
  int b = blockIdx.x, tid = threadIdx.x;
  if (b < 816) {
    int i4 = b*256 + tid;
    const float* src; unsigned short* dst;
    if (i4 < 131072)      { src = ipw; dst = wip; }
    else if (i4 < 143360) { i4 -= 131072; src = xpw; dst = wxp; }
    else                  { i4 -= 143360; src = opw; dst = wop; }
    float4 v = ((const float4*)src)[i4];
    ushort4v o;
    o.x = f2bf(v.x); o.y = f2bf(v.y); o.z = f2bf(v.z); o.w = f2bf(v.w);
    ((ushort4v*)dst)[i4] = o;
  } else {
    int idx = (b-816)*256 + tid;               // t*256 + d
    int t = idx >> 8, d = idx & 255;
    float acc = fib[d];
#pragma unroll
    for (int i = 0; i < D_IN; ++i) acc += x[t*D_IN+i]*fiw[d*D_IN+i];
    h[idx] = acc;
  }
}

// ---- bf16 MFMA GEMM, BK=64: C[MxN] (+)= A[MxK] @ B[NxK]^T ----
template<int WM, int WN, bool RMS, bool ACC, bool ABF16, bool CBF16>
__global__ __launch_bounds__(256) void k_gemm_mfma(
    const void* __restrict__ Ap, const unsigned short* __restrict__ B,
    void* __restrict__ Cp, int M, int N, int K, const float* __restrict__ nwp)
{
  constexpr int BM = 32*WM, BN = 32*WN, LDT = 72;   // 64 + 8 pad (16B-aligned rows)
  const float* A = (const float*)Ap;
  const unsigned short* Ab = (const unsigned short*)Ap;
  float* Cf = (float*)Cp;
  unsigned short* Cb = (unsigned short*)Cp;
  __shared__ unsigned short As[BM*LDT];
  __shared__ unsigned short Bs[BN*LDT];
  __shared__ float rms_lds[BM];
  __shared__ float nws[D_MODEL];
  const int tid = threadIdx.x;
  const int bm = blockIdx.x*BM, bn = blockIdx.y*BN;
  const int w = tid >> 6, lane = tid & 63;
  const int mb = (w>>1)*WM*16, nb = (w&1)*WN*16;
  const int lr = lane & 15, lk = (lane>>4)*8;
  if (RMS) {
    nws[tid] = nwp[tid];                       // 256 threads == D_MODEL
    constexpr int TPR = 256/BM;                // threads per row
    constexpr int SEG = D_MODEL/TPR;           // cols per thread
    int row = tid / TPR, part = tid % TPR;
    const float* ap = A + (size_t)(bm+row)*K + part*SEG;
    float s = 0.f;
#pragma unroll
    for (int i = 0; i < SEG; i += 4) {
      float4 v = *(const float4*)&ap[i];
      s += v.x*v.x + v.y*v.y + v.z*v.z + v.w*v.w;
    }
#pragma unroll
    for (int m = TPR>>1; m; m >>= 1) s += __shfl_xor(s, m);
    if (part == 0) rms_lds[row] = rsqrtf(s*(1.f/D_MODEL) + EPS);
    __syncthreads();
  }
  f32x4 acc[WM][WN] = {};
  for (int k0 = 0; k0 < K; k0 += 64) {
#pragma unroll 2
    for (int s = tid; s < BM*8; s += 256) {
      int row = s>>3, kg = (s&7)*8;
      if (ABF16) {
        *(ushort8*)&As[row*LDT+kg] = *(const ushort8*)&Ab[(size_t)(bm+row)*K + k0 + kg];
      } else {
        const float* ap = &A[(size_t)(bm+row)*K + k0 + kg];
        float4 a0 = *(const float4*)ap, a1 = *(const float4*)(ap+4);
        if (RMS) {
          float rs = rms_lds[row];
          a0.x *= rs*nws[k0+kg+0]; a0.y *= rs*nws[k0+kg+1];
          a0.z *= rs*nws[k0+kg+2]; a0.w *= rs*nws[k0+kg+3];
          a1.x *= rs*nws[k0+kg+4]; a1.y *= rs*nws[k0+kg+5];
          a1.z *= rs*nws[k0+kg+6]; a1.w *= rs*nws[k0+kg+7];
        }
        ushort8 o;
        o[0]=f2bf(a0.x); o[1]=f2bf(a0.y); o[2]=f2bf(a0.z); o[3]=f2bf(a0.w);
        o[4]=f2bf(a1.x); o[5]=f2bf(a1.y); o[6]=f2bf(a1.z); o[7]=f2bf(a1.w);
        *(ushort8*)&As[row*LDT+kg] = o;
      }
    }
#pragma unroll 2
    for (int s = tid; s < BN*8; s += 256) {
      int row = s>>3, kg = (s&7)*8;
      *(ushort8*)&Bs[row*LDT+kg] = *(const ushort8*)&B[(size_t)(bn+row)*K + k0 + kg];
    }
    __syncthreads();
#pragma unroll
    for (int kk = 0; kk < 2; ++kk) {
      short8 af[WM], bfr[WN];
#pragma unroll
      for (int i = 0; i < WM; ++i) af[i]  = *(const short8*)&As[(mb+i*16+lr)*LDT + kk*32 + lk];
#pragma unroll
      for (int j = 0; j < WN; ++j) bfr[j] = *(const short8*)&Bs[(nb+j*16+lr)*LDT + kk*32 + lk];
#pragma unroll
      for (int i = 0; i < WM; ++i)
#pragma unroll
        for (int j = 0; j < WN; ++j)
          acc[i][j] = __builtin_amdgcn_mfma_f32_16x16x32_bf16(af[i], bfr[j], acc[i][j], 0, 0, 0);
    }
    __syncthreads();
  }
  // D layout: col = lane&15, row = (lane>>4)*4 + r
#pragma unroll
  for (int i = 0; i < WM; ++i)
#pragma unroll
    for (int j = 0; j < WN; ++j) {
      int col = bn + nb + j*16 + lr;
#pragma unroll
      for (int r = 0; r < 4; ++r) {
        int row = bm + mb + i*16 + (lane>>4)*4 + r;
        size_t o = (size_t)row*N + col;
        if (CBF16)      Cb[o] = f2bf(acc[i][j][r]);
        else if (ACC)   Cf[o] = Cf[o] + acc[i][j][r];
        else            Cf[o] = acc[i][j][r];
      }
    }
}

// ---- conv + silu + x_proj + dt_proj + scan phase 1, one block per 16-row chunk ----
__global__ __launch_bounds__(512) void k_cxps1(
    const unsigned short* __restrict__ xzb, const float* __restrict__ cw,
    const float* __restrict__ cb, const unsigned short* __restrict__ wxp,
    const float* __restrict__ dtw, const float* __restrict__ dtb,
    const float* __restrict__ alog, float* __restrict__ dbc,
    float* __restrict__ S, unsigned short* __restrict__ Q)
{
  constexpr int LDA = ED + 8;   // 520 ushorts per row
  __shared__ unsigned short As[CHUNK*LDA];
  __shared__ float Ds[CHUNK][DT_RANK];
  __shared__ float Bsh[CHUNK][NSTATE];
  const int tid = threadIdx.x;
  const int e = tid;
  const int c = blockIdx.x;
  const int t0 = c*CHUNK;
  float cwv[KCONV];
#pragma unroll
  for (int k = 0; k < KCONV; ++k) cwv[k] = cw[e*KCONV+k];
  float cbv = cb[e];
  float w0=0.f, w1=0.f, w2=0.f;
  if (t0 > 0) {
    w0 = bf2f(xzb[(size_t)(t0-3)*(2*ED) + e]);
    w1 = bf2f(xzb[(size_t)(t0-2)*(2*ED) + e]);
    w2 = bf2f(xzb[(size_t)(t0-1)*(2*ED) + e]);
  }
  float xv[CHUNK];
#pragma unroll
  for (int t = 0; t < CHUNK; ++t) {
    float cur = bf2f(xzb[(size_t)(t0+t)*(2*ED) + e]);
    float v = siluf_(cbv + w0*cwv[0] + w1*cwv[1] + w2*cwv[2] + cur*cwv[3]);
    xv[t] = v;
    w0=w1; w1=w2; w2=cur;
  }
#pragma unroll
  for (int t = 0; t < CHUNK; ++t) {
    unsigned int us = f2bf(xv[t]);
    unsigned int other = (unsigned int)__shfl_down((int)us, 1);
    if ((tid & 1) == 0) *(unsigned int*)&As[t*LDA + e] = us | (other << 16);
  }
  __syncthreads();
  const int w = tid >> 6, lane = tid & 63;
  const int lr = lane & 15, lk = (lane>>4)*8;
  if (w < 3) {
    f32x4 acc = {};
#pragma unroll
    for (int ks = 0; ks < ED/32; ++ks) {
      short8 af = *(const short8*)&As[lr*LDA + ks*32 + lk];
      short8 bf = *(const short8*)&wxp[(size_t)(w*16+lr)*ED + ks*32 + lk];
      acc = __builtin_amdgcn_mfma_f32_16x16x32_bf16(af, bf, acc, 0, 0, 0);
    }
#pragma unroll
    for (int r = 0; r < 4; ++r) {
      int row = (lane>>4)*4 + r;
      dbc[(size_t)(t0+row)*48 + w*16 + lr] = acc[r];
      if (w == 0) Ds[row][lr] = acc[r];
      else if (w == 1) Bsh[row][lr] = acc[r];
    }
  }
  __syncthreads();
  float dtwv[DT_RANK];
#pragma unroll
  for (int r = 0; r < DT_RANK; ++r) dtwv[r] = dtw[e*DT_RANK+r];
  float dtbv = dtb[e];
  float A[NSTATE], h[NSTATE];
#pragma unroll
  for (int n = 0; n < NSTATE; ++n) { A[n] = -__expf(alog[e*NSTATE+n]); h[n] = 0.f; }
  float sd = 0.f;
#pragma unroll
  for (int t = 0; t < CHUNK; ++t) {
    float da = dtbv;
#pragma unroll
    for (int r = 0; r < DT_RANK; ++r) da += Ds[t][r]*dtwv[r];
    float d = softplusf_(da);
    sd += d;
    float dx = d*xv[t];
#pragma unroll
    for (int n = 0; n < NSTATE; ++n)
      h[n] = __expf(d*A[n])*h[n] + dx*Bsh[t][n];
  }
  S[(size_t)c*ED + e] = sd;
#pragma unroll
  for (int n = 0; n < NSTATE; ++n) Q[(size_t)(c*NSTATE+n)*ED + e] = f2bf(h[n]);
}

// Phase 2: segmented affine scan. 256 blocks x 512 thr; block = 32 channels x 16 segs.
__global__ __launch_bounds__(512) void k_scan2(
    const float* __restrict__ alog, const float* __restrict__ S,
    unsigned short* __restrict__ Q)
{
  constexpr int NSEG = 16, STEPS = NCHUNK/NSEG;   // 16 x 16
  __shared__ float Pl[NSEG][32], Rl[NSEG][32], Hs[NSEG][32];
  const int tid = threadIdx.x;
  const int seg = tid >> 5, chl = tid & 31;
  const int ch = blockIdx.x*32 + chl;
  const int n = ch >> 9, e = ch & 511;
  const float a = -__expf(alog[e*NSTATE+n]);
  const int c0 = seg*STEPS;
  float ev[STEPS], qv[STEPS];
#pragma unroll
  for (int k = 0; k < STEPS; ++k) ev[k] = S[(size_t)(c0+k)*ED + e];
#pragma unroll
  for (int k = 0; k < STEPS; ++k) qv[k] = bf2f(Q[(size_t)((c0+k)*NSTATE+n)*ED + e]);
#pragma unroll
  for (int k = 0; k < STEPS; ++k) ev[k] = __expf(a*ev[k]);
  float P = 1.f, R = 0.f;
#pragma unroll
  for (int k = 0; k < STEPS; ++k) { R = ev[k]*R + qv[k]; P *= ev[k]; }
  Pl[seg][chl] = P; Rl[seg][chl] = R;
  __syncthreads();
  if (tid < 32) {
    float hcur = 0.f;
#pragma unroll
    for (int s = 0; s < NSEG; ++s) { Hs[s][tid] = hcur; hcur = Pl[s][tid]*hcur + Rl[s][tid]; }
  }
  __syncthreads();
  float h = Hs[seg][chl];
#pragma unroll
  for (int k = 0; k < STEPS; ++k) {
    float hl = qv[k];
    Q[(size_t)((c0+k)*NSTATE+n)*ED + e] = f2bf(h);
    h = ev[k]*h + hl;
  }
}

// Phase 3: recompute conv from bf16 xi; replay chunk with true Hin (bf16);
// fuse dt_proj, C-dot, D-skip, silu(z); emit bf16 y. One block per chunk.
__global__ __launch_bounds__(512) void k_scan3(
    const unsigned short* __restrict__ xzb, const float* __restrict__ dbc,
    const float* __restrict__ cw, const float* __restrict__ cb,
    const float* __restrict__ dtw, const float* __restrict__ dtb,
    const float* __restrict__ alog, const unsigned short* __restrict__ Hin,
    const float* __restrict__ Dv, unsigned short* __restrict__ y)
{
  __shared__ float Ds[CHUNK][DT_RANK];
  __shared__ float Bsh[CHUNK][NSTATE];
  __shared__ float Cs[CHUNK][NSTATE];
  const int tid = threadIdx.x;
  const int e = tid;
  const int c = blockIdx.x;
  const int t0 = c*CHUNK;
  for (int i = tid; i < CHUNK*48; i += 512) {
    int t = i/48, col = i - t*48;
    float v = dbc[(size_t)(t0+t)*48 + col];
    if (col < DT_RANK) Ds[t][col] = v;
    else if (col < DT_RANK+NSTATE) Bsh[t][col-DT_RANK] = v;
    else Cs[t][col-DT_RANK-NSTATE] = v;
  }
  // conv recompute (identical arithmetic to k_cxps1 -> identical values)
  float cwv[KCONV];
#pragma unroll
  for (int k = 0; k < KCONV; ++k) cwv[k] = cw[e*KCONV+k];
  float cbv = cb[e];
  float w0=0.f, w1=0.f, w2=0.f;
  if (t0 > 0) {
    w0 = bf2f(xzb[(size_t)(t0-3)*(2*ED) + e]);
    w1 = bf2f(xzb[(size_t)(t0-2)*(2*ED) + e]);
    w2 = bf2f(xzb[(size_t)(t0-1)*(2*ED) + e]);
  }
  float x[CHUNK], z[CHUNK];
#pragma unroll
  for (int t = 0; t < CHUNK; ++t) {
    float cur = bf2f(xzb[(size_t)(t0+t)*(2*ED) + e]);
    x[t] = siluf_(cbv + w0*cwv[0] + w1*cwv[1] + w2*cwv[2] + cur*cwv[3]);
    w0=w1; w1=w2; w2=cur;
  }
#pragma unroll
  for (int t = 0; t < CHUNK; ++t) z[t] = bf2f(xzb[(size_t)(t0+t)*(2*ED) + ED + e]);
  __syncthreads();
  float dtwv[DT_RANK];
#pragma unroll
  for (int r = 0; r < DT_RANK; ++r) dtwv[r] = dtw[e*DT_RANK+r];
  float dtbv = dtb[e];
  float A[NSTATE], h[NSTATE];
#pragma unroll
  for (int n = 0; n < NSTATE; ++n) {
    A[n] = -__expf(alog[e*NSTATE+n]);
    h[n] = bf2f(Hin[(size_t)(c*NSTATE+n)*ED + e]);
  }
  float dv = Dv[e];
#pragma unroll
  for (int t = 0; t < CHUNK; ++t) {
    float da = dtbv;
#pragma unroll
    for (int r = 0; r < DT_RANK; ++r) da += Ds[t][r]*dtwv[r];
    float d = softplusf_(da);
    float dx = d*x[t];
    float ysum = 0.f;
#pragma unroll
    for (int n = 0; n < NSTATE; ++n) {
      h[n] = __expf(d*A[n])*h[n] + dx*Bsh[t][n];
      ysum += h[n]*Cs[t][n];
    }
    y[(size_t)(t0+t)*ED + e] = f2bf((ysum + dv*x[t]) * siluf_(z[t]));
  }
}

// out[t] = tanh( h[t][:] . fc_out_w + fc_out_b ) — one wave per row
__global__ void k_fc_out(const float* __restrict__ h, const float* __restrict__ w,
                         const float* __restrict__ b, float* __restrict__ out){
  int wave = threadIdx.x >> 6, lane = threadIdx.x & 63;
  int row = blockIdx.x*4 + wave;
  const float4 hv = *(const float4*)&h[row*D_MODEL + lane*4];
  const float4 wv = *(const float4*)&w[lane*4];
  float s = hv.x*wv.x + hv.y*wv.y + hv.z*wv.z + hv.w*wv.w;
#pragma unroll
  for (int m = 32; m; m >>= 1) s += __shfl_xor(s, m);
  if (lane == 0) out[row] = tanhf(s + b[0]);
}

extern "C" void kernel_launch(void* const* d_in, const int* in_sizes, int n_in,
                              void* d_out, int out_size, void* d_ws, size_t ws_size,
                              hipStream_t stream){
  const float* x    = (const float*)d_in[0];
  const float* fiw  = (const float*)d_in[1];
  const float* fib  = (const float*)d_in[2];
  const float* fow  = (const float*)d_in[3];
  const float* fob  = (const float*)d_in[4];
  const float* nw   = (const float*)d_in[5];
  const float* ipw  = (const float*)d_in[6];
  const float* cw   = (const float*)d_in[7];
  const float* cb   = (const float*)d_in[8];
  const float* xpw  = (const float*)d_in[9];
  const float* dtw  = (const float*)d_in[10];
  const float* dtb  = (const float*)d_in[11];
  const float* alog = (const float*)d_in[12];
  const float* Dv   = (const float*)d_in[13];
  const float* opw  = (const float*)d_in[14];

  float* W = (float*)d_ws;
  float* h   = W;                                   // L*256 fp32
  float* dbc = h   + (size_t)LSEQ*D_MODEL;          // L*48 fp32
  float* S   = dbc + (size_t)LSEQ*48;               // 256*512 fp32
  unsigned short* xzb = (unsigned short*)(S + (size_t)NCHUNK*ED); // L*1024 bf16
  unsigned short* Q   = xzb + (size_t)LSEQ*2*ED;    // 256*16*512 bf16 (Hin in-place)
  unsigned short* yb  = Q   + (size_t)NCHUNK*NSTATE*ED; // L*512 bf16
  unsigned short* wip = yb  + (size_t)LSEQ*ED;      // 2*1024*256
  unsigned short* wxp = wip + (size_t)2*2*ED*D_MODEL; // 2*48*512
  unsigned short* wop = wxp + (size_t)2*48*ED;      // 2*256*512

  k_prep<<<816 + LSEQ, 256, 0, stream>>>(x, fiw, fib, ipw, xpw, opw, h, wip, wxp, wop);

  for (int l = 0; l < 2; ++l) {
    const unsigned short* wip_l = wip + (size_t)l*2*ED*D_MODEL;
    const unsigned short* wxp_l = wxp + (size_t)l*48*ED;
    const unsigned short* wop_l = wop + (size_t)l*D_MODEL*ED;
    const float* nw_l   = nw   + l*D_MODEL;
    const float* cw_l   = cw   + l*ED*KCONV;
    const float* cb_l   = cb   + l*ED;
    const float* dtw_l  = dtw  + l*ED*DT_RANK;
    const float* dtb_l  = dtb  + l*ED;
    const float* alog_l = alog + l*ED*NSTATE;
    const float* D_l    = Dv   + l*ED;

    // in_proj: BM=32,BN=64 -> 128x16 = 2048 blocks (8 blocks/CU, 32 waves/CU)
    k_gemm_mfma<1,2,true,false,false,true><<<dim3(LSEQ/32, (2*ED)/64), 256, 0, stream>>>(
        h, wip_l, xzb, LSEQ, 2*ED, D_MODEL, nw_l);
    k_cxps1<<<NCHUNK, 512, 0, stream>>>(xzb, cw_l, cb_l, wxp_l, dtw_l, dtb_l, alog_l,
                                        dbc, S, Q);
    k_scan2<<<ED*NSTATE/32, 512, 0, stream>>>(alog_l, S, Q);
    k_scan3<<<NCHUNK, 512, 0, stream>>>(xzb, dbc, cw_l, cb_l, dtw_l, dtb_l, alog_l,
                                        Q, D_l, yb);
    // out_proj: BM=BN=32 -> 128x8 = 1024 blocks (4 blocks/CU)
    k_gemm_mfma<1,1,false,true,true,false><<<dim3(LSEQ/32, D_MODEL/32), 256, 0, stream>>>(
        yb, wop_l, h, LSEQ, D_MODEL, ED, nullptr);
  }

  k_fc_out<<<LSEQ/4, 256, 0, stream>>>(h, fow, fob, (float*)d_out);
}